// Round 1
// baseline (104.094 us; speedup 1.0000x reference)
//
#include <hip/hip_runtime.h>
#include <math.h>

#define NB 128
#define NR 36
#define NT 128
#define ND 1024
#define TT 64      // tokens per block
#define KC 128     // k/d chunk width
#define STR 132    // padded LDS row stride (33 float4s, coprime with 8 superbanks)

__global__ __launch_bounds__(512)
void scan_fused(const float* __restrict__ img, const float* __restrict__ cap,
                float* __restrict__ out) {
    __shared__ float img_c[NR][STR];   // 19008 B
    __shared__ float cap_c[TT][STR];   // 33792 B
    __shared__ float w_s[NR][TT];      //  9216 B
    __shared__ float ni_s[NR];
    __shared__ float nc_s[TT];

    const int tid = threadIdx.x;
    const int b   = blockIdx.x >> 1;
    const int t0  = (blockIdx.x & 1) * TT;

    const float* imgB = img + (size_t)b * NR * ND;
    const float* capB = cap + ((size_t)b * NT + t0) * ND;
    float*       outB = out + ((size_t)b * NT + t0) * ND;

    const int wv = tid >> 6, lane = tid & 63;

    // ---------- norms (coalesced global reads + wave shuffle reduce) ----------
    for (int r = wv; r < NR; r += 8) {
        float s = 0.f;
        #pragma unroll
        for (int j = 0; j < 16; ++j) { float v = imgB[r*ND + j*64 + lane]; s = fmaf(v, v, s); }
        #pragma unroll
        for (int off = 32; off; off >>= 1) s += __shfl_xor(s, off, 64);
        if (lane == 0) ni_s[r] = sqrtf(s);
    }
    for (int t = wv; t < TT; t += 8) {
        float s = 0.f;
        #pragma unroll
        for (int j = 0; j < 16; ++j) { float v = capB[t*ND + j*64 + lane]; s = fmaf(v, v, s); }
        #pragma unroll
        for (int off = 32; off; off >>= 1) s += __shfl_xor(s, off, 64);
        if (lane == 0) nc_s[t] = sqrtf(s);
    }

    // ---------- phase 1: raw dots  scores[r][t] = <img[r,:], cap[t,:]> ----------
    const int t  = tid & 63;   // token within tile
    const int ty = tid >> 6;   // 0..7 region-group
    float acc[5] = {0.f, 0.f, 0.f, 0.f, 0.f};

    for (int kc = 0; kc < ND; kc += KC) {
        __syncthreads();  // previous-iteration readers done before overwrite
        // stage img chunk 36 x 128 (coalesced)
        for (int f = tid; f < NR*32; f += 512) {
            int r = f >> 5, c4 = f & 31;
            *(float4*)(&img_c[r][c4*4]) = *(const float4*)(imgB + r*ND + kc + c4*4);
        }
        // stage cap chunk 64 x 128 (coalesced)
        for (int f = tid; f < TT*32; f += 512) {
            int tt = f >> 5, c4 = f & 31;
            *(float4*)(&cap_c[tt][c4*4]) = *(const float4*)(capB + tt*ND + kc + c4*4);
        }
        __syncthreads();
        #pragma unroll 8
        for (int k4 = 0; k4 < KC/4; ++k4) {
            const float4 c = *(const float4*)(&cap_c[t][k4*4]);
            #pragma unroll
            for (int i = 0; i < 5; ++i) {
                int r = ty + 8*i;
                if (r < NR) {
                    const float4 a = *(const float4*)(&img_c[r][k4*4]);
                    acc[i] = fmaf(a.x, c.x, acc[i]);
                    acc[i] = fmaf(a.y, c.y, acc[i]);
                    acc[i] = fmaf(a.z, c.z, acc[i]);
                    acc[i] = fmaf(a.w, c.w, acc[i]);
                }
            }
        }
    }
    #pragma unroll
    for (int i = 0; i < 5; ++i) {
        int r = ty + 8*i;
        if (r < NR) w_s[r][t] = acc[i];
    }
    __syncthreads();

    // ---------- softmax over regions (wave 0, one lane per token) ----------
    if (tid < TT) {
        float sc[NR];
        const float nct = nc_s[tid];
        float m = -1e30f;
        #pragma unroll
        for (int r = 0; r < NR; ++r) {
            float denom = fmaxf(ni_s[r] * nct, 1e-8f);
            float v = w_s[r][tid] / denom;
            sc[r] = v;
            m = fmaxf(m, v);
        }
        float sum = 0.f;
        #pragma unroll
        for (int r = 0; r < NR; ++r) { sc[r] = __expf(sc[r] - m); sum += sc[r]; }
        const float inv = 1.f / sum;
        #pragma unroll
        for (int r = 0; r < NR; ++r) w_s[r][tid] = sc[r] * inv;
    }

    // ---------- phase 2: out[t][d] = sum_r w[r][t] * img[r][d] ----------
    const int d4   = tid & 31;   // float4 column within chunk
    const int trow = tid >> 5;   // 0..15

    for (int dc = 0; dc < ND; dc += KC) {
        __syncthreads();  // softmax done (first iter) / previous readers done
        for (int f = tid; f < NR*32; f += 512) {
            int r = f >> 5, c4 = f & 31;
            *(float4*)(&img_c[r][c4*4]) = *(const float4*)(imgB + r*ND + dc + c4*4);
        }
        __syncthreads();
        float4 o0 = {0,0,0,0}, o1 = {0,0,0,0}, o2 = {0,0,0,0}, o3 = {0,0,0,0};
        #pragma unroll 4
        for (int r = 0; r < NR; ++r) {
            const float4 a = *(const float4*)(&img_c[r][d4*4]);
            const float w0 = w_s[r][trow];
            const float w1 = w_s[r][trow + 16];
            const float w2 = w_s[r][trow + 32];
            const float w3 = w_s[r][trow + 48];
            o0.x = fmaf(w0, a.x, o0.x); o0.y = fmaf(w0, a.y, o0.y);
            o0.z = fmaf(w0, a.z, o0.z); o0.w = fmaf(w0, a.w, o0.w);
            o1.x = fmaf(w1, a.x, o1.x); o1.y = fmaf(w1, a.y, o1.y);
            o1.z = fmaf(w1, a.z, o1.z); o1.w = fmaf(w1, a.w, o1.w);
            o2.x = fmaf(w2, a.x, o2.x); o2.y = fmaf(w2, a.y, o2.y);
            o2.z = fmaf(w2, a.z, o2.z); o2.w = fmaf(w2, a.w, o2.w);
            o3.x = fmaf(w3, a.x, o3.x); o3.y = fmaf(w3, a.y, o3.y);
            o3.z = fmaf(w3, a.z, o3.z); o3.w = fmaf(w3, a.w, o3.w);
        }
        *(float4*)(outB + (size_t)(trow      )*ND + dc + d4*4) = o0;
        *(float4*)(outB + (size_t)(trow + 16)*ND + dc + d4*4) = o1;
        *(float4*)(outB + (size_t)(trow + 32)*ND + dc + d4*4) = o2;
        *(float4*)(outB + (size_t)(trow + 48)*ND + dc + d4*4) = o3;
    }
}

extern "C" void kernel_launch(void* const* d_in, const int* in_sizes, int n_in,
                              void* d_out, int out_size, void* d_ws, size_t ws_size,
                              hipStream_t stream) {
    const float* img = (const float*)d_in[0];  // [B, R, D]
    const float* cap = (const float*)d_in[1];  // [B, T, D]
    // d_in[2] = cap_mask, unused (as in reference)
    float* out = (float*)d_out;                // [B, T, D] f32

    scan_fused<<<NB * 2, 512, 0, stream>>>(img, cap, out);
}

// Round 2
// 65.387 us; speedup vs baseline: 1.5920x; 1.5920x over previous
//
#include <hip/hip_runtime.h>
#include <math.h>

#define NB 128
#define NR 36
#define NT 128
#define ND 1024
#define TTA 64          // tokens per scores-block
#define SA 136          // bf16 LDS row stride (128 + 8) -> 2-way (free) frag reads

typedef float f32x4_t __attribute__((ext_vector_type(4)));
typedef short bf16x8_t __attribute__((ext_vector_type(8)));

__device__ __forceinline__ ushort f2bf(float f) {
    // round-to-nearest-even f32 -> bf16 (inputs are finite)
    unsigned int u = __float_as_uint(f);
    return (ushort)((u + 0x7fffu + ((u >> 16) & 1u)) >> 16);
}

// ---------------- Kernel A: cosine scores + softmax over regions ----------------
__global__ __launch_bounds__(512)
void scores_softmax(const float* __restrict__ img, const float* __restrict__ cap,
                    float* __restrict__ w_ws) {
    __shared__ __align__(16) ushort cap_s[TTA][SA];   // 17408 B (bf16)
    __shared__ __align__(16) ushort img_s[48][SA];    // 13056 B (rows 36..47 garbage, never consumed)
    __shared__ float sc_s[TTA][49];                   // 12544 B
    __shared__ float ni_s[NR];
    __shared__ float nc_s[TTA];

    const int tid = threadIdx.x;
    const int b   = blockIdx.x >> 1;
    const int t0  = (blockIdx.x & 1) * TTA;
    const float* imgB = img + (size_t)b * NR * ND;
    const float* capB = cap + ((size_t)b * NT + t0) * ND;

    const int wv = tid >> 6, lane = tid & 63;

    // ---- f32 norms (the cold HBM read; staging below re-hits L2) ----
    for (int r = wv; r < NR; r += 8) {
        float s = 0.f;
        #pragma unroll
        for (int i = 0; i < 4; ++i) {
            const float4 v = *(const float4*)(imgB + r*ND + i*256 + lane*4);
            s = fmaf(v.x,v.x,fmaf(v.y,v.y,fmaf(v.z,v.z,fmaf(v.w,v.w,s))));
        }
        #pragma unroll
        for (int off = 32; off; off >>= 1) s += __shfl_xor(s, off, 64);
        if (lane == 0) ni_s[r] = sqrtf(s);
    }
    for (int t = wv; t < TTA; t += 8) {
        float s = 0.f;
        #pragma unroll
        for (int i = 0; i < 4; ++i) {
            const float4 v = *(const float4*)(capB + t*ND + i*256 + lane*4);
            s = fmaf(v.x,v.x,fmaf(v.y,v.y,fmaf(v.z,v.z,fmaf(v.w,v.w,s))));
        }
        #pragma unroll
        for (int off = 32; off; off >>= 1) s += __shfl_xor(s, off, 64);
        if (lane == 0) nc_s[t] = sqrtf(s);
    }

    // ---- bf16 MFMA dots: D[token][region], K=1024 split over 2 wave-groups ----
    const int grp   = wv >> 2;        // k-half owner
    const int mfrag = wv & 3;         // 16-token row-fragment
    const int nrow  = lane & 15;
    const int kgrp  = (lane >> 4) * 8;
    f32x4_t acc0 = {0.f,0.f,0.f,0.f}, acc1 = acc0, acc2 = acc0;

    for (int kc = 0; kc < ND; kc += 128) {
        __syncthreads();
        // stage cap 64x128 f32 -> bf16 (coalesced: one wave per row-span)
        #pragma unroll
        for (int i = 0; i < 4; ++i) {
            const int idx = tid + 512*i;                 // 2048 float4
            const int row = idx >> 5, c4 = idx & 31;
            const float4 v = *(const float4*)(capB + row*ND + kc + c4*4);
            ushort4 h; h.x = f2bf(v.x); h.y = f2bf(v.y); h.z = f2bf(v.z); h.w = f2bf(v.w);
            *(ushort4*)(&cap_s[row][c4*4]) = h;
        }
        // stage img 36x128
        #pragma unroll
        for (int i = 0; i < 3; ++i) {
            const int idx = tid + 512*i;                 // 1152 float4
            if (idx < NR*32) {
                const int row = idx >> 5, c4 = idx & 31;
                const float4 v = *(const float4*)(imgB + row*ND + kc + c4*4);
                ushort4 h; h.x = f2bf(v.x); h.y = f2bf(v.y); h.z = f2bf(v.z); h.w = f2bf(v.w);
                *(ushort4*)(&img_s[row][c4*4]) = h;
            }
        }
        __syncthreads();
        const int kb = grp * 64;
        #pragma unroll
        for (int ks = 0; ks < 2; ++ks) {
            const int ko = kb + ks*32 + kgrp;
            const bf16x8_t a  = *(const bf16x8_t*)(&cap_s[mfrag*16 + nrow][ko]);
            const bf16x8_t b0 = *(const bf16x8_t*)(&img_s[nrow][ko]);
            const bf16x8_t b1 = *(const bf16x8_t*)(&img_s[16 + nrow][ko]);
            const bf16x8_t b2 = *(const bf16x8_t*)(&img_s[32 + nrow][ko]);
            acc0 = __builtin_amdgcn_mfma_f32_16x16x32_bf16(a, b0, acc0, 0, 0, 0);
            acc1 = __builtin_amdgcn_mfma_f32_16x16x32_bf16(a, b1, acc1, 0, 0, 0);
            acc2 = __builtin_amdgcn_mfma_f32_16x16x32_bf16(a, b2, acc2, 0, 0, 0);
        }
    }

    // combine k-halves in LDS (C/D layout: col=lane&15, row=(lane>>4)*4+reg)
    const int trow = mfrag*16 + (lane >> 4) * 4;
    __syncthreads();
    if (grp == 0) {
        #pragma unroll
        for (int j = 0; j < 4; ++j) {
            sc_s[trow+j][nrow]      = acc0[j];
            sc_s[trow+j][16+nrow]   = acc1[j];
            sc_s[trow+j][32+nrow]   = acc2[j];
        }
    }
    __syncthreads();
    if (grp == 1) {
        #pragma unroll
        for (int j = 0; j < 4; ++j) {
            sc_s[trow+j][nrow]      += acc0[j];
            sc_s[trow+j][16+nrow]   += acc1[j];
            sc_s[trow+j][32+nrow]   += acc2[j];
        }
    }
    __syncthreads();

    // ---- softmax over r (36) per token, f32, one thread per token ----
    if (tid < TTA) {
        const float nct = nc_s[tid];
        float v[NR];
        float m = -1e30f;
        #pragma unroll
        for (int r = 0; r < NR; ++r) {
            const float d = fmaxf(ni_s[r] * nct, 1e-8f);
            v[r] = sc_s[tid][r] / d;
            m = fmaxf(m, v[r]);
        }
        float sum = 0.f;
        #pragma unroll
        for (int r = 0; r < NR; ++r) { v[r] = __expf(v[r] - m); sum += v[r]; }
        const float inv = 1.f / sum;
        float* wO = w_ws + ((size_t)b * NT + t0 + tid) * NR;
        #pragma unroll
        for (int q = 0; q < 9; ++q) {
            float4 o; o.x = v[q*4]*inv; o.y = v[q*4+1]*inv; o.z = v[q*4+2]*inv; o.w = v[q*4+3]*inv;
            *(float4*)(wO + q*4) = o;
        }
    }
}

// ---------------- Kernel B: out[t][d] = sum_r w[t][r] * img[r][d] (f32) ----------------
__global__ __launch_bounds__(512)
void pool(const float* __restrict__ img, const float* __restrict__ w_ws,
          float* __restrict__ out) {
    __shared__ float w_s[NR][32];
    const int tid = threadIdx.x;
    const int b   = blockIdx.x >> 2;
    const int t0  = (blockIdx.x & 3) * 32;
    const float* imgB = img + (size_t)b * NR * ND;
    const float* wB   = w_ws + ((size_t)b * NT + t0) * NR;
    float* outB       = out + ((size_t)b * NT + t0) * ND;

    for (int f = tid; f < 32*NR; f += 512) {
        const int t = f / NR, r = f - t*NR;
        w_s[r][t] = wB[f];
    }
    __syncthreads();

    const int d4 = tid & 255;       // float4 column (256 x 4 = D)
    const int tg = tid >> 8;        // token half (16 tokens each)

    float4 o[16];
    #pragma unroll
    for (int i = 0; i < 16; ++i) { o[i].x = 0.f; o[i].y = 0.f; o[i].z = 0.f; o[i].w = 0.f; }

    #pragma unroll 4
    for (int r = 0; r < NR; ++r) {
        const float4 a  = *(const float4*)(imgB + r*ND + d4*4);
        const float4 w0 = *(const float4*)(&w_s[r][tg*16]);
        const float4 w1 = *(const float4*)(&w_s[r][tg*16 + 4]);
        const float4 w2 = *(const float4*)(&w_s[r][tg*16 + 8]);
        const float4 w3 = *(const float4*)(&w_s[r][tg*16 + 12]);
        #define FMA4(oo, s) { oo.x = fmaf(s, a.x, oo.x); oo.y = fmaf(s, a.y, oo.y); \
                              oo.z = fmaf(s, a.z, oo.z); oo.w = fmaf(s, a.w, oo.w); }
        FMA4(o[0],  w0.x) FMA4(o[1],  w0.y) FMA4(o[2],  w0.z) FMA4(o[3],  w0.w)
        FMA4(o[4],  w1.x) FMA4(o[5],  w1.y) FMA4(o[6],  w1.z) FMA4(o[7],  w1.w)
        FMA4(o[8],  w2.x) FMA4(o[9],  w2.y) FMA4(o[10], w2.z) FMA4(o[11], w2.w)
        FMA4(o[12], w3.x) FMA4(o[13], w3.y) FMA4(o[14], w3.z) FMA4(o[15], w3.w)
        #undef FMA4
    }

    #pragma unroll
    for (int i = 0; i < 16; ++i)
        *(float4*)(outB + (size_t)(tg*16 + i)*ND + d4*4) = o[i];
}

extern "C" void kernel_launch(void* const* d_in, const int* in_sizes, int n_in,
                              void* d_out, int out_size, void* d_ws, size_t ws_size,
                              hipStream_t stream) {
    const float* img = (const float*)d_in[0];   // [B, R, D]
    const float* cap = (const float*)d_in[1];   // [B, T, D]
    float* out  = (float*)d_out;                // [B, T, D]
    float* w_ws = (float*)d_ws;                 // [B, T, R] weights, 2.36 MB

    scores_softmax<<<NB * 2, 512, 0, stream>>>(img, cap, w_ws);
    pool<<<NB * 4, 512, 0, stream>>>(img, w_ws, out);
}

// Round 3
// 58.537 us; speedup vs baseline: 1.7783x; 1.1170x over previous
//
#include <hip/hip_runtime.h>
#include <math.h>

#define NB 128
#define NR 36
#define NT 128
#define ND 1024
#define TT 64          // tokens per block
#define KC 256         // cap K-chunk
#define NCH 4          // ND/KC
#define IST 1048       // img_s stride (f16): 2096 B -> 2-way bank pattern (free)
#define CST 264        // cap_s stride (f16): 528 B  -> 2-way bank pattern (free)
#define SST 52         // sc_s stride (f32)

typedef float    f32x4 __attribute__((ext_vector_type(4)));
typedef _Float16 f16x8 __attribute__((ext_vector_type(8)));
typedef _Float16 f16x4 __attribute__((ext_vector_type(4)));

__global__ __launch_bounds__(1024)
void scan_fused(const float* __restrict__ img, const float* __restrict__ cap,
                float* __restrict__ out) {
    __shared__ __align__(16) _Float16 img_s[NR][IST];   // 75456 B (full K)
    __shared__ __align__(16) _Float16 cap_s[TT][CST];   // 33792 B (one K-chunk)
    __shared__ __align__(16) float    sc_s[TT][SST];    // 13312 B (scores -> weights)
    __shared__ float ni_s[NR];
    __shared__ float nc_s[TT];

    const int tid = threadIdx.x;
    // XCD-pair swizzle: both token-halves of a batch land on the same XCD
    const int phys = blockIdx.x;
    const int lb   = (phys & 7) * 32 + (phys >> 3);
    const int b    = lb >> 1;
    const int t0   = (lb & 1) * TT;

    const float* imgB = img + (size_t)b * NR * ND;
    const float* capB = cap + ((size_t)b * NT + t0) * ND;
    float*       outB = out + ((size_t)b * NT + t0) * ND;

    const int wv = tid >> 6, lane = tid & 63, ln = lane & 15, hi = lane >> 4;

    // ---- zero-init reduction targets ----
    for (int i = tid; i < TT * SST; i += 1024) ((float*)sc_s)[i] = 0.f;
    if (tid < NR) ni_s[tid] = 0.f;

    // ---- stage img f32 -> f16 LDS, accumulate exact-f32 norm partials ----
    float nip[9];
    #pragma unroll
    for (int i = 0; i < 9; ++i) {
        const int idx = tid + 1024 * i;        // 9216 float4 total
        const int r = idx >> 8, c4 = idx & 255;
        const float4 v = *(const float4*)(imgB + r * ND + c4 * 4);
        nip[i] = fmaf(v.x, v.x, fmaf(v.y, v.y, fmaf(v.z, v.z, v.w * v.w)));
        f16x4 h; h[0] = (_Float16)v.x; h[1] = (_Float16)v.y;
                 h[2] = (_Float16)v.z; h[3] = (_Float16)v.w;
        *(f16x4*)(&img_s[r][c4 * 4]) = h;
    }
    // prefetch cap chunk 0 into registers
    float4 cpre[4];
    #pragma unroll
    for (int i = 0; i < 4; ++i)
        cpre[i] = *(const float4*)(capB + ((tid >> 6) + 16 * i) * ND + (tid & 63) * 4);

    __syncthreads();   // img_s + zero-init visible

    // ni reduce: within a wave all lanes share the same row set {tid>>8 + 4i}
    #pragma unroll
    for (int i = 0; i < 9; ++i) {
        float s = nip[i];
        #pragma unroll
        for (int off = 32; off; off >>= 1) s += __shfl_xor(s, off, 64);
        if (lane == 0) atomicAdd(&ni_s[(tid >> 8) + 4 * i], s);
    }

    // ---- cap chunk loop: stage + norm accum + MFMA scores ----
    const int mf = wv & 3;         // token fragment
    const int kq = wv >> 2;        // K quarter
    float ncp[4] = {0.f, 0.f, 0.f, 0.f};
    f32x4 acc[3] = {{0.f,0.f,0.f,0.f},{0.f,0.f,0.f,0.f},{0.f,0.f,0.f,0.f}};

    for (int kc = 0; kc < NCH; ++kc) {
        #pragma unroll
        for (int i = 0; i < 4; ++i) {
            const int row = (tid >> 6) + 16 * i;     // whole wave shares row set
            const float4 v = cpre[i];
            ncp[i] = fmaf(v.x, v.x, fmaf(v.y, v.y, fmaf(v.z, v.z, fmaf(v.w, v.w, ncp[i]))));
            f16x4 h; h[0] = (_Float16)v.x; h[1] = (_Float16)v.y;
                     h[2] = (_Float16)v.z; h[3] = (_Float16)v.w;
            *(f16x4*)(&cap_s[row][(tid & 63) * 4]) = h;
        }
        if (kc + 1 < NCH) {
            #pragma unroll
            for (int i = 0; i < 4; ++i)
                cpre[i] = *(const float4*)(capB + ((tid >> 6) + 16 * i) * ND
                                           + (kc + 1) * KC + (tid & 63) * 4);
        }
        __syncthreads();
        const int kg = kc * KC + kq * 64;
        #pragma unroll
        for (int ks = 0; ks < 2; ++ks) {
            const f16x8 a = *(const f16x8*)(&cap_s[mf * 16 + ln][kq * 64 + ks * 32 + hi * 8]);
            #pragma unroll
            for (int nf = 0; nf < 3; ++nf) {
                // nf==2 rows 36..47 read garbage (stays inside block LDS);
                // those columns are ignored by the softmax (r < 36).
                const f16x8 bb = *(const f16x8*)(&img_s[0][0]
                                    + (size_t)(nf * 16 + ln) * IST + kg + ks * 32 + hi * 8);
                acc[nf] = __builtin_amdgcn_mfma_f32_16x16x32_f16(a, bb, acc[nf], 0, 0, 0);
            }
        }
        __syncthreads();
    }

    // combine K-quarters: C/D layout col=lane&15, row=(lane>>4)*4+reg
    const int tb = mf * 16 + hi * 4;
    #pragma unroll
    for (int nf = 0; nf < 3; ++nf)
        #pragma unroll
        for (int j = 0; j < 4; ++j)
            atomicAdd(&sc_s[tb + j][nf * 16 + ln], acc[nf][j]);

    // nc reduce (one wave owns each row set {wv + 16i}) + ni sqrt
    #pragma unroll
    for (int i = 0; i < 4; ++i) {
        float s = ncp[i];
        #pragma unroll
        for (int off = 32; off; off >>= 1) s += __shfl_xor(s, off, 64);
        if (lane == 0) nc_s[wv + 16 * i] = sqrtf(s);
    }
    if (tid < NR) ni_s[tid] = sqrtf(ni_s[tid]);   // atomics drained at prior barriers
    __syncthreads();

    // ---- softmax over regions (one thread per token), weights back to sc_s ----
    if (tid < TT) {
        const float nct = nc_s[tid];
        float v[NR];
        float m = -1e30f;
        #pragma unroll
        for (int r = 0; r < NR; ++r) {
            const float d = fmaxf(ni_s[r] * nct, 1e-8f);
            v[r] = sc_s[tid][r] / d;
            m = fmaxf(m, v[r]);
        }
        float sum = 0.f;
        #pragma unroll
        for (int r = 0; r < NR; ++r) { v[r] = __expf(v[r] - m); sum += v[r]; }
        const float inv = 1.f / sum;
        #pragma unroll
        for (int r = 0; r < NR; ++r) sc_s[tid][r] = v[r] * inv;
    }
    __syncthreads();

    // ---- pool: out[t][d] = sum_r w[t][r] * img_f16[r][d] ----
    const int q = tid >> 7;        // token-oct (8 tokens), uniform per 2 waves
    const int g = tid & 127;       // d-group: d = dq*512 + g*4

    float4 o[16];                  // [t 8][dq 2]
    #pragma unroll
    for (int i = 0; i < 16; ++i) { o[i].x = 0.f; o[i].y = 0.f; o[i].z = 0.f; o[i].w = 0.f; }

    for (int rq = 0; rq < 9; ++rq) {
        float4 w4[8];
        #pragma unroll
        for (int t = 0; t < 8; ++t)
            w4[t] = *(const float4*)(&sc_s[q * 8 + t][rq * 4]);   // broadcast reads
        #pragma unroll
        for (int j = 0; j < 4; ++j) {
            const int r = rq * 4 + j;
            #pragma unroll
            for (int dq = 0; dq < 2; ++dq) {
                const f16x4 ih = *(const f16x4*)(&img_s[r][dq * 512 + g * 4]);
                float4 im; im.x = (float)ih[0]; im.y = (float)ih[1];
                           im.z = (float)ih[2]; im.w = (float)ih[3];
                #pragma unroll
                for (int t = 0; t < 8; ++t) {
                    const float ww = ((const float*)&w4[t])[j];
                    float4& oo = o[t * 2 + dq];
                    oo.x = fmaf(ww, im.x, oo.x); oo.y = fmaf(ww, im.y, oo.y);
                    oo.z = fmaf(ww, im.z, oo.z); oo.w = fmaf(ww, im.w, oo.w);
                }
            }
        }
    }
    #pragma unroll
    for (int t = 0; t < 8; ++t)
        #pragma unroll
        for (int dq = 0; dq < 2; ++dq)
            *(float4*)(outB + (size_t)(q * 8 + t) * ND + dq * 512 + g * 4) = o[t * 2 + dq];
}

extern "C" void kernel_launch(void* const* d_in, const int* in_sizes, int n_in,
                              void* d_out, int out_size, void* d_ws, size_t ws_size,
                              hipStream_t stream) {
    const float* img = (const float*)d_in[0];   // [B, R, D]
    const float* cap = (const float*)d_in[1];   // [B, T, D]
    float* out = (float*)d_out;                 // [B, T, D]
    scan_fused<<<NB * 2, 1024, 0, stream>>>(img, cap, out);
}